// Round 22
// baseline (14275.438 us; speedup 1.0000x reference)
//
#include <hip/hip_runtime.h>
#include <hip/hip_bf16.h>
#include <cfloat>

// FPS matching the np reference bit-exactly (R7: PASS, absmax 0).
// FROZEN per-point arithmetic: dx=px-cx; y2=dy*dy; inner=fma(dx,dx,y2);
// d=fma(dz,dz,inner); nd=fminf(dist,d); winner=(max value, smallest index).
// R22: pruning validated exact in R21; rebuild the harness: 512thr, fixed
// 64-pt chunks of the cell-sorted order; chunk(w,k) = wave w's lanes at
// register row k -> ds/pz register-resident, STATIC indexing only; xy in
// LDS; lane-parallel bound checks + ballot; no atomics; no global loads in
// the scan; DPP reduces; 3 barriers/step. Skip test: bound*0.999 > chunkmax
// => fminf no-op for every point (exact by induction; tight boxes, margin
// covers ~2e-6 relative fp error). Winner: value-max then max-inv-origidx
// among ds==v* in chunks with cmax==v* -- handles cross-chunk ties exactly.

typedef unsigned long long u64;
#define CELLS 512
#define PREP_T 512
#define FPS_T 512
#define NCHUNK 256

template <int CTRL>
__device__ __forceinline__ float dpp_maxf(float v) {
  int iv = __float_as_int(v);
  int sh = __builtin_amdgcn_update_dpp(iv, iv, CTRL, 0xF, 0xF, false);
  return fmaxf(v, __int_as_float(sh));
}
template <int CTRL>
__device__ __forceinline__ unsigned dpp_maxu(unsigned v) {
  int sh = __builtin_amdgcn_update_dpp((int)v, (int)v, CTRL, 0xF, 0xF, false);
  return ((unsigned)sh > v) ? (unsigned)sh : v;
}
__device__ __forceinline__ float wave_maxf(float v) {
  v = dpp_maxf<0xB1>(v); v = dpp_maxf<0x4E>(v); v = dpp_maxf<0x141>(v);
  v = dpp_maxf<0x140>(v); v = dpp_maxf<0x142>(v); v = dpp_maxf<0x143>(v);
  return __int_as_float(__builtin_amdgcn_readlane(__float_as_int(v), 63));
}
__device__ __forceinline__ unsigned wave_maxu(unsigned v) {
  v = dpp_maxu<0xB1>(v); v = dpp_maxu<0x4E>(v); v = dpp_maxu<0x141>(v);
  v = dpp_maxu<0x140>(v); v = dpp_maxu<0x142>(v); v = dpp_maxu<0x143>(v);
  return (unsigned)__builtin_amdgcn_readlane((int)v, 63);
}

__global__ __launch_bounds__(PREP_T) void prep_kernel(
    const float* __restrict__ xyz, float4* __restrict__ rp,
    float* __restrict__ cbb, int N) {
  const int b = blockIdx.x, t = threadIdx.x;
  const float* xb = xyz + (size_t)b * N * 3;
  __shared__ int s_cnt[CELLS], s_start[CELLS], s_off[CELLS];
  __shared__ float s_red[8][6];
  __shared__ float s_bb[6];
  const int PPT = N / PREP_T;
  const int wave = t >> 6, lane = t & 63;

  float mnx = FLT_MAX, mny = FLT_MAX, mnz = FLT_MAX;
  float mxx = -FLT_MAX, mxy = -FLT_MAX, mxz = -FLT_MAX;
  for (int k = 0; k < PPT; ++k) {
    int p = k * PREP_T + t;
    float x = xb[(size_t)p * 3], y = xb[(size_t)p * 3 + 1], z = xb[(size_t)p * 3 + 2];
    mnx = fminf(mnx, x); mny = fminf(mny, y); mnz = fminf(mnz, z);
    mxx = fmaxf(mxx, x); mxy = fmaxf(mxy, y); mxz = fmaxf(mxz, z);
  }
  for (int off = 32; off > 0; off >>= 1) {
    mnx = fminf(mnx, __shfl_xor(mnx, off, 64));
    mny = fminf(mny, __shfl_xor(mny, off, 64));
    mnz = fminf(mnz, __shfl_xor(mnz, off, 64));
    mxx = fmaxf(mxx, __shfl_xor(mxx, off, 64));
    mxy = fmaxf(mxy, __shfl_xor(mxy, off, 64));
    mxz = fmaxf(mxz, __shfl_xor(mxz, off, 64));
  }
  if (lane == 0) {
    s_red[wave][0] = mnx; s_red[wave][1] = mny; s_red[wave][2] = mnz;
    s_red[wave][3] = mxx; s_red[wave][4] = mxy; s_red[wave][5] = mxz;
  }
  __syncthreads();
  if (t == 0) {
    float a = s_red[0][0], bq = s_red[0][1], c = s_red[0][2];
    float d = s_red[0][3], e = s_red[0][4], g = s_red[0][5];
    for (int w = 1; w < 8; ++w) {
      a = fminf(a, s_red[w][0]); bq = fminf(bq, s_red[w][1]); c = fminf(c, s_red[w][2]);
      d = fmaxf(d, s_red[w][3]); e = fmaxf(e, s_red[w][4]); g = fmaxf(g, s_red[w][5]);
    }
    s_bb[0] = a; s_bb[1] = bq; s_bb[2] = c; s_bb[3] = d; s_bb[4] = e; s_bb[5] = g;
  }
  if (t < CELLS) s_cnt[t] = 0;
  __syncthreads();

  float lox = s_bb[0], loy = s_bb[1], loz = s_bb[2];
  float rx = s_bb[3] - lox, ry = s_bb[4] - loy, rz = s_bb[5] - loz;
  float sx = (rx > 0.f) ? 8.f / rx : 0.f;
  float sy = (ry > 0.f) ? 8.f / ry : 0.f;
  float sz = (rz > 0.f) ? 8.f / rz : 0.f;

#define CIDX(v, lo, sc) ({ int cc_ = (int)(((v) - (lo)) * (sc)); cc_ < 0 ? 0 : (cc_ > 7 ? 7 : cc_); })

  for (int k = 0; k < PPT; ++k) {
    int p = k * PREP_T + t;
    float x = xb[(size_t)p * 3], y = xb[(size_t)p * 3 + 1], z = xb[(size_t)p * 3 + 2];
    int cid = (CIDX(x, lox, sx) << 6) | (CIDX(y, loy, sy) << 3) | CIDX(z, loz, sz);
    atomicAdd(&s_cnt[cid], 1);
  }
  __syncthreads();
  if (t < CELLS) s_start[t] = s_cnt[t];
  __syncthreads();
  for (int off = 1; off < CELLS; off <<= 1) {
    int add = 0;
    if (t < CELLS && t >= off) add = s_start[t - off];
    __syncthreads();
    if (t < CELLS) s_start[t] += add;
    __syncthreads();
  }
  if (t < CELLS) { s_start[t] -= s_cnt[t]; s_off[t] = 0; }
  __syncthreads();

  for (int k = 0; k < PPT; ++k) {
    int p = k * PREP_T + t;
    float x = xb[(size_t)p * 3], y = xb[(size_t)p * 3 + 1], z = xb[(size_t)p * 3 + 2];
    int cid = (CIDX(x, lox, sx) << 6) | (CIDX(y, loy, sy) << 3) | CIDX(z, loz, sz);
    int pos = s_start[cid] + atomicAdd(&s_off[cid], 1);
    rp[(size_t)b * N + pos] =
        make_float4(x, y, z, __uint_as_float(0xFFFFFFFFu - (unsigned)p));
  }
  __syncthreads();

  // chunk bboxes over 64 consecutive sorted points (rp just written, same CU)
  const float4* rpb = rp + (size_t)b * N;
  for (int c = wave; c < NCHUNK; c += PREP_T / 64) {
    float4 q = rpb[c * 64 + lane];
    float a0 = q.x, a1 = q.y, a2 = q.z, a3 = q.x, a4 = q.y, a5 = q.z;
    for (int off = 32; off > 0; off >>= 1) {
      a0 = fminf(a0, __shfl_xor(a0, off, 64));
      a1 = fminf(a1, __shfl_xor(a1, off, 64));
      a2 = fminf(a2, __shfl_xor(a2, off, 64));
      a3 = fmaxf(a3, __shfl_xor(a3, off, 64));
      a4 = fmaxf(a4, __shfl_xor(a4, off, 64));
      a5 = fmaxf(a5, __shfl_xor(a5, off, 64));
    }
    if (lane == 0) {
      float* o = cbb + ((size_t)b * NCHUNK + c) * 6;
      o[0] = a0; o[1] = a1; o[2] = a2; o[3] = a3; o[4] = a4; o[5] = a5;
    }
  }
}

__global__ __launch_bounds__(FPS_T)
void fps_kernel(const float* __restrict__ xyz, const float4* __restrict__ rp,
                const float* __restrict__ cbb, int* __restrict__ out_idx,
                int N, int S) {
#pragma clang fp contract(off)
  const int b = blockIdx.x, t = threadIdx.x;
  const int wave = t >> 6, lane = t & 63;
  const float4* rpb = rp + (size_t)b * N;

  __shared__ float2 s_xy[16384];        // 128 KB
  __shared__ float s_cbb[NCHUNK * 6];   // 6 KB
  __shared__ float s_cmax[NCHUNK];      // 1 KB (wave-private per chunk)
  __shared__ float s_vpart[8];
  __shared__ unsigned s_ipart[8];
  __shared__ float s_cent[3];

  float pz[32], ds[32];   // STATIC indexing only (rule #20)
#pragma unroll
  for (int k = 0; k < 32; ++k) {
    float4 q = rpb[(size_t)k * FPS_T + t];
    s_xy[k * FPS_T + t] = make_float2(q.x, q.y);
    pz[k] = q.z;
    ds[k] = FLT_MAX;
  }
  for (int i = t; i < NCHUNK * 6; i += FPS_T) s_cbb[i] = cbb[(size_t)b * NCHUNK * 6 + i];
  for (int i = t; i < NCHUNK; i += FPS_T) s_cmax[i] = FLT_MAX;
  if (t == 0) {
    s_cent[0] = xyz[(size_t)b * N * 3 + 0];
    s_cent[1] = xyz[(size_t)b * N * 3 + 1];
    s_cent[2] = xyz[(size_t)b * N * 3 + 2];
  }
  unsigned g_orig = 0;
  __syncthreads();

  for (int s = 0; s < S; ++s) {
    if (t == 0) out_idx[(size_t)b * S + s] = (int)g_orig;
    float cx = s_cent[0], cy = s_cent[1], cz = s_cent[2];

    // A: lane-parallel bound check of this wave's 32 owned chunks
    bool act = false;
    if (lane < 32) {
      int c = lane * 8 + wave;
      float mv = s_cmax[c];
      const float* bb = &s_cbb[c * 6];
      float gx = fmaxf(0.f, fmaxf(bb[0] - cx, cx - bb[3]));
      float gy = fmaxf(0.f, fmaxf(bb[1] - cy, cy - bb[4]));
      float gz = fmaxf(0.f, fmaxf(bb[2] - cz, cz - bb[5]));
      float bound = gx * gx + gy * gy + gz * gz;
      act = (bound * 0.999f <= mv);
    }
    unsigned mask = (unsigned)__ballot(act);

    // B: scan active chunks (FROZEN chain; register dist; LDS xy)
#pragma unroll
    for (int k = 0; k < 32; ++k) {
      if (mask & (1u << k)) {
        float2 xy = s_xy[k * FPS_T + t];
        float dx = xy.x - cx, dy = xy.y - cy, dz = pz[k] - cz;
        float y2 = dy * dy;
        float inner = __builtin_fmaf(dx, dx, y2);
        float dd = __builtin_fmaf(dz, dz, inner);
        float nd = fminf(ds[k], dd);
        ds[k] = nd;
        float wm = wave_maxf(nd);
        if (lane == 0) s_cmax[k * 8 + wave] = wm;
      }
    }

    // value phase: wave partial over its own 32 chunks (fresh or stale-exact)
    float mv2 = (lane < 32) ? s_cmax[lane * 8 + wave] : -FLT_MAX;
    float wv = wave_maxf(mv2);
    if (lane == 0) s_vpart[wave] = wv;
    __syncthreads();  // bar1
    float vstar = s_vpart[0];
#pragma unroll
    for (int i = 1; i < 8; ++i) vstar = fmaxf(vstar, s_vpart[i]);

    // index phase: max inverted-orig-idx among points with ds == vstar
    bool hit = false;
    if (lane < 32) hit = (s_cmax[lane * 8 + wave] == vstar);
    unsigned hmask = (unsigned)__ballot(hit);
    unsigned cand = 0;
    if (hmask) {
#pragma unroll
      for (int k = 0; k < 32; ++k) {
        if (hmask & (1u << k)) {
          if (ds[k] == vstar) {
            unsigned iv = __float_as_uint(
                ((const float*)&rpb[(size_t)k * FPS_T + t])[3]);
            cand = cand > iv ? cand : iv;
          }
        }
      }
    }
    unsigned wi = wave_maxu(cand);
    if (lane == 0) s_ipart[wave] = wi;
    __syncthreads();  // bar2
    unsigned ginv = s_ipart[0];
#pragma unroll
    for (int i = 1; i < 8; ++i) ginv = ginv > s_ipart[i] ? ginv : s_ipart[i];
    g_orig = 0xFFFFFFFFu - ginv;

    // winner lane publishes next centroid coords
    if (hmask) {
#pragma unroll
      for (int k = 0; k < 32; ++k) {
        if (hmask & (1u << k)) {
          if (ds[k] == vstar) {
            unsigned iv = __float_as_uint(
                ((const float*)&rpb[(size_t)k * FPS_T + t])[3]);
            if (iv == ginv) {
              float2 xy = s_xy[k * FPS_T + t];
              s_cent[0] = xy.x; s_cent[1] = xy.y; s_cent[2] = pz[k];
            }
          }
        }
      }
    }
    __syncthreads();  // bar3
  }
}

// Gather: out = [ xyz[b][idx[b][s]][c] (B*S*3) , feat[b][idx[b][s]][:] (B*S*C) ]
__global__ void gather_kernel(const float* __restrict__ xyz,
                              const float* __restrict__ feat,
                              const int* __restrict__ idx,
                              float* __restrict__ out,
                              int B, int N, int S, int C) {
  const int c4pr = C >> 2;
  const int nf4 = B * S * c4pr;
  int tid = blockIdx.x * blockDim.x + threadIdx.x;
  if (tid < nf4) {
    int c4 = tid % c4pr;
    int bs = tid / c4pr;
    int s = bs % S, b = bs / S;
    int p = idx[b * S + s];
    const float4* src = (const float4*)(feat + ((size_t)b * N + p) * C);
    float4* dst = (float4*)(out + (size_t)B * S * 3 + ((size_t)bs) * C);
    dst[c4] = src[c4];
  } else {
    int t2 = tid - nf4;
    int nxyz = B * S * 3;
    if (t2 < nxyz) {
      int c = t2 % 3;
      int bs = t2 / 3;
      int s = bs % S, b = bs / S;
      int p = idx[b * S + s];
      out[t2] = xyz[((size_t)b * N + p) * 3 + c];
    }
  }
}

extern "C" void kernel_launch(void* const* d_in, const int* in_sizes, int n_in,
                              void* d_out, int out_size, void* d_ws, size_t ws_size,
                              hipStream_t stream) {
  const float* xyz = (const float*)d_in[0];
  const float* feat = (const float*)d_in[1];
  float* out = (float*)d_out;

  const int B = 32;
  const int N = in_sizes[0] / (B * 3);        // 16384
  const int C = in_sizes[1] / (B * N);        // 128
  const int S = N / 4;                        // 4096

  // ws: idx 512KB | rp 8MB | cbb 196KB
  int* d_idx = (int*)d_ws;
  float4* d_rp = (float4*)((char*)d_ws + (size_t)B * S * sizeof(int));
  float* d_cbb = (float*)((char*)d_rp + (size_t)B * N * sizeof(float4));

  prep_kernel<<<B, PREP_T, 0, stream>>>(xyz, d_rp, d_cbb, N);
  fps_kernel<<<B, FPS_T, 0, stream>>>(xyz, d_rp, d_cbb, d_idx, N, S);

  int total = B * S * (C >> 2) + B * S * 3;
  int blocks = (total + 255) / 256;
  gather_kernel<<<blocks, 256, 0, stream>>>(xyz, feat, d_idx, out, B, N, S, C);
}

// Round 23
// 10211.661 us; speedup vs baseline: 1.3980x; 1.3980x over previous
//
#include <hip/hip_runtime.h>
#include <hip/hip_bf16.h>
#include <cfloat>

// FPS matching the np reference bit-exactly (R7: PASS, absmax 0).
// FROZEN per-point arithmetic: dx=px-cx; y2=dy*dy; inner=fma(dx,dx,y2);
// d=fma(dz,dz,inner); nd=fminf(dist,d); winner=(max value, smallest index).
// R23: row-pruned FPS with minimal per-step overhead. 32 rows x 512 sorted
// pts; row boxes in regs; rowmax parity-double-buffered (stale-high safe);
// skip unsafe cross-wave rowmax reads eliminated (read cur, write next,
// own-slot only). Argmax always over all 32 register ds (exact regardless
// of pruning). Tie-resolve from packed 16-bit orig idx in regs. 2 barriers,
// no atomics, no global loads in the step loop.

typedef unsigned long long u64;
#define CELLS 512
#define PREP_T 512
#define FPS_T 512

template <int CTRL>
__device__ __forceinline__ float dpp_maxf(float v) {
  int iv = __float_as_int(v);
  int sh = __builtin_amdgcn_update_dpp(iv, iv, CTRL, 0xF, 0xF, false);
  return fmaxf(v, __int_as_float(sh));
}
template <int CTRL>
__device__ __forceinline__ unsigned dpp_maxu(unsigned v) {
  int sh = __builtin_amdgcn_update_dpp((int)v, (int)v, CTRL, 0xF, 0xF, false);
  return ((unsigned)sh > v) ? (unsigned)sh : v;
}
// 6-step DPP chain; lane 63 ends with the wave max (no broadcast).
__device__ __forceinline__ float wave_maxf_tail(float v) {
  v = dpp_maxf<0xB1>(v); v = dpp_maxf<0x4E>(v); v = dpp_maxf<0x141>(v);
  v = dpp_maxf<0x140>(v); v = dpp_maxf<0x142>(v); v = dpp_maxf<0x143>(v);
  return v;
}
__device__ __forceinline__ unsigned wave_maxu_bcast(unsigned v) {
  v = dpp_maxu<0xB1>(v); v = dpp_maxu<0x4E>(v); v = dpp_maxu<0x141>(v);
  v = dpp_maxu<0x140>(v); v = dpp_maxu<0x142>(v); v = dpp_maxu<0x143>(v);
  return (unsigned)__builtin_amdgcn_readlane((int)v, 63);
}

__global__ __launch_bounds__(PREP_T) void prep_kernel(
    const float* __restrict__ xyz, float4* __restrict__ rp,
    float* __restrict__ rbb, int N) {
  const int b = blockIdx.x, t = threadIdx.x;
  const float* xb = xyz + (size_t)b * N * 3;
  __shared__ int s_cnt[CELLS], s_start[CELLS], s_off[CELLS];
  __shared__ float s_red[8][6];
  __shared__ float s_bb[6];
  const int PPT = N / PREP_T;
  const int wave = t >> 6, lane = t & 63;

  float mnx = FLT_MAX, mny = FLT_MAX, mnz = FLT_MAX;
  float mxx = -FLT_MAX, mxy = -FLT_MAX, mxz = -FLT_MAX;
  for (int k = 0; k < PPT; ++k) {
    int p = k * PREP_T + t;
    float x = xb[(size_t)p * 3], y = xb[(size_t)p * 3 + 1], z = xb[(size_t)p * 3 + 2];
    mnx = fminf(mnx, x); mny = fminf(mny, y); mnz = fminf(mnz, z);
    mxx = fmaxf(mxx, x); mxy = fmaxf(mxy, y); mxz = fmaxf(mxz, z);
  }
  for (int off = 32; off > 0; off >>= 1) {
    mnx = fminf(mnx, __shfl_xor(mnx, off, 64));
    mny = fminf(mny, __shfl_xor(mny, off, 64));
    mnz = fminf(mnz, __shfl_xor(mnz, off, 64));
    mxx = fmaxf(mxx, __shfl_xor(mxx, off, 64));
    mxy = fmaxf(mxy, __shfl_xor(mxy, off, 64));
    mxz = fmaxf(mxz, __shfl_xor(mxz, off, 64));
  }
  if (lane == 0) {
    s_red[wave][0] = mnx; s_red[wave][1] = mny; s_red[wave][2] = mnz;
    s_red[wave][3] = mxx; s_red[wave][4] = mxy; s_red[wave][5] = mxz;
  }
  __syncthreads();
  if (t == 0) {
    float a = s_red[0][0], bq = s_red[0][1], c = s_red[0][2];
    float d = s_red[0][3], e = s_red[0][4], g = s_red[0][5];
    for (int w = 1; w < 8; ++w) {
      a = fminf(a, s_red[w][0]); bq = fminf(bq, s_red[w][1]); c = fminf(c, s_red[w][2]);
      d = fmaxf(d, s_red[w][3]); e = fmaxf(e, s_red[w][4]); g = fmaxf(g, s_red[w][5]);
    }
    s_bb[0] = a; s_bb[1] = bq; s_bb[2] = c; s_bb[3] = d; s_bb[4] = e; s_bb[5] = g;
  }
  if (t < CELLS) s_cnt[t] = 0;
  __syncthreads();

  float lox = s_bb[0], loy = s_bb[1], loz = s_bb[2];
  float rx = s_bb[3] - lox, ry = s_bb[4] - loy, rz = s_bb[5] - loz;
  float sx = (rx > 0.f) ? 8.f / rx : 0.f;
  float sy = (ry > 0.f) ? 8.f / ry : 0.f;
  float sz = (rz > 0.f) ? 8.f / rz : 0.f;

#define CIDX(v, lo, sc) ({ int cc_ = (int)(((v) - (lo)) * (sc)); cc_ < 0 ? 0 : (cc_ > 7 ? 7 : cc_); })

  for (int k = 0; k < PPT; ++k) {
    int p = k * PREP_T + t;
    float x = xb[(size_t)p * 3], y = xb[(size_t)p * 3 + 1], z = xb[(size_t)p * 3 + 2];
    int cid = (CIDX(x, lox, sx) << 6) | (CIDX(y, loy, sy) << 3) | CIDX(z, loz, sz);
    atomicAdd(&s_cnt[cid], 1);
  }
  __syncthreads();
  if (t < CELLS) s_start[t] = s_cnt[t];
  __syncthreads();
  for (int off = 1; off < CELLS; off <<= 1) {
    int add = 0;
    if (t < CELLS && t >= off) add = s_start[t - off];
    __syncthreads();
    if (t < CELLS) s_start[t] += add;
    __syncthreads();
  }
  if (t < CELLS) { s_start[t] -= s_cnt[t]; s_off[t] = 0; }
  __syncthreads();

  for (int k = 0; k < PPT; ++k) {
    int p = k * PREP_T + t;
    float x = xb[(size_t)p * 3], y = xb[(size_t)p * 3 + 1], z = xb[(size_t)p * 3 + 2];
    int cid = (CIDX(x, lox, sx) << 6) | (CIDX(y, loy, sy) << 3) | CIDX(z, loz, sz);
    int pos = s_start[cid] + atomicAdd(&s_off[cid], 1);
    rp[(size_t)b * N + pos] =
        make_float4(x, y, z, __uint_as_float(0xFFFFFFFFu - (unsigned)p));
  }
  __syncthreads();

  // row boxes: 32 rows of 512 consecutive sorted points
  const float4* rpb = rp + (size_t)b * N;
  for (int r = wave; r < 32; r += PREP_T / 64) {
    float a0 = FLT_MAX, a1 = FLT_MAX, a2 = FLT_MAX;
    float a3 = -FLT_MAX, a4 = -FLT_MAX, a5 = -FLT_MAX;
    for (int i = 0; i < 8; ++i) {
      float4 q = rpb[r * 512 + i * 64 + lane];
      a0 = fminf(a0, q.x); a1 = fminf(a1, q.y); a2 = fminf(a2, q.z);
      a3 = fmaxf(a3, q.x); a4 = fmaxf(a4, q.y); a5 = fmaxf(a5, q.z);
    }
    for (int off = 32; off > 0; off >>= 1) {
      a0 = fminf(a0, __shfl_xor(a0, off, 64));
      a1 = fminf(a1, __shfl_xor(a1, off, 64));
      a2 = fminf(a2, __shfl_xor(a2, off, 64));
      a3 = fmaxf(a3, __shfl_xor(a3, off, 64));
      a4 = fmaxf(a4, __shfl_xor(a4, off, 64));
      a5 = fmaxf(a5, __shfl_xor(a5, off, 64));
    }
    if (lane == 0) {
      float* o = rbb + ((size_t)b * 32 + r) * 6;
      o[0] = a0; o[1] = a1; o[2] = a2; o[3] = a3; o[4] = a4; o[5] = a5;
    }
  }
}

__global__ __launch_bounds__(FPS_T, 2)
void fps_kernel(const float* __restrict__ xyz, const float4* __restrict__ rp,
                const float* __restrict__ rbb, int* __restrict__ out_idx,
                int N, int S) {
#pragma clang fp contract(off)
  const int b = blockIdx.x, t = threadIdx.x;
  const int wave = t >> 6, lane = t & 63;
  const float4* rpb = rp + (size_t)b * N;

  __shared__ float2 s_xy[16384];          // 128 KB
  __shared__ float s_rowmax[2][8][32];    // 2 KB, parity-double-buffered
  __shared__ float s_vpart[8];
  __shared__ unsigned s_ipart[8];
  __shared__ float s_cand[8][3];

  float pz[32], ds[32];       // static indexing only
  unsigned ivp[16];           // packed inv16 per row
#pragma unroll
  for (int k = 0; k < 16; ++k) ivp[k] = 0;
#pragma unroll
  for (int k = 0; k < 32; ++k) {
    float4 q = rpb[(size_t)k * FPS_T + t];
    s_xy[k * FPS_T + t] = make_float2(q.x, q.y);
    pz[k] = q.z;
    ds[k] = FLT_MAX;
    unsigned p = 0xFFFFFFFFu - __float_as_uint(q.w);
    unsigned inv16 = 0xFFFFu - p;
    ivp[k >> 1] |= inv16 << ((k & 1) * 16);
  }
  // lane r (<32) holds row r's box
  float bx0 = 0, by0 = 0, bz0 = 0, bx1 = 0, by1 = 0, bz1 = 0;
  if (lane < 32) {
    const float* bb = rbb + ((size_t)b * 32 + lane) * 6;
    bx0 = bb[0]; by0 = bb[1]; bz0 = bb[2];
    bx1 = bb[3]; by1 = bb[4]; bz1 = bb[5];
  }
  if (t < 256) {
    s_rowmax[0][t >> 5][t & 31] = FLT_MAX;
    s_rowmax[1][t >> 5][t & 31] = FLT_MAX;
  }
  if (t < 8) s_ipart[t] = (t == 0) ? 0xFFFFu : 0u;  // inv16 of p=0
  if (t == 0) {
    s_cand[0][0] = xyz[(size_t)b * N * 3 + 0];
    s_cand[0][1] = xyz[(size_t)b * N * 3 + 1];
    s_cand[0][2] = xyz[(size_t)b * N * 3 + 2];
  }
  __syncthreads();

  for (int s = 0; s < S; ++s) {
    // resolve winner of previous step (or initial state)
    unsigned ginv = s_ipart[0];
    int wstar = 0;
#pragma unroll
    for (int w = 1; w < 8; ++w) {
      unsigned v = s_ipart[w];
      if (v > ginv) { ginv = v; wstar = w; }
    }
    if (t == 0) out_idx[(size_t)b * S + s] = (int)(0xFFFFu - ginv);
    float cx = s_cand[wstar][0], cy = s_cand[wstar][1], cz = s_cand[wstar][2];

    const int cur = s & 1, nxt = cur ^ 1;

    // skip test (reads cur buffer only; conflict-free [j][lane])
    bool act = false;
    if (lane < 32) {
      float cm = s_rowmax[cur][0][lane];
#pragma unroll
      for (int j = 1; j < 8; ++j) cm = fmaxf(cm, s_rowmax[cur][j][lane]);
      float gx = fmaxf(0.f, fmaxf(bx0 - cx, cx - bx1));
      float gy = fmaxf(0.f, fmaxf(by0 - cy, cy - by1));
      float gz = fmaxf(0.f, fmaxf(bz0 - cz, cz - bz1));
      float bound = gx * gx + gy * gy + gz * gz;
      act = (bound * 0.999f <= cm);
      // copy-forward own-wave slot (scan overwrites active rows after this;
      // stale-high values are conservative-safe)
      s_rowmax[nxt][wave][lane] = s_rowmax[cur][wave][lane];
    }
    unsigned mask = (unsigned)__ballot(act);

    // scan active rows: FROZEN chain; write own-wave rowmax to next buffer
#pragma unroll
    for (int k = 0; k < 32; ++k) {
      if (mask & (1u << k)) {
        float2 xy = s_xy[k * FPS_T + t];
        float dx = xy.x - cx, dy = xy.y - cy, dz = pz[k] - cz;
        float y2 = dy * dy;
        float inner = __builtin_fmaf(dx, dx, y2);
        float dd = __builtin_fmaf(dz, dz, inner);
        float nd = fminf(ds[k], dd);
        ds[k] = nd;
        float rm = wave_maxf_tail(nd);
        if (lane == 63) s_rowmax[nxt][wave][k] = rm;
      }
    }

    // exact argmax: all 32 register ds (independent of pruning)
    float bestv = ds[0];
#pragma unroll
    for (int k = 1; k < 32; ++k) bestv = fmaxf(bestv, ds[k]);
    float wv = wave_maxf_tail(bestv);
    if (lane == 63) s_vpart[wave] = wv;
    __syncthreads();  // bar1

    float vstar = s_vpart[0];
#pragma unroll
    for (int w = 1; w < 8; ++w) vstar = fmaxf(vstar, s_vpart[w]);

    // tie-resolve: min orig p == max inv16 among ds==vstar (rare threads)
    unsigned cand = 0;
    int ck2 = 0;
    if (bestv == vstar) {
#pragma unroll
      for (int k = 0; k < 32; ++k) {
        if (ds[k] == vstar) {
          unsigned iv = (ivp[k >> 1] >> ((k & 1) * 16)) & 0xFFFFu;
          if (iv > cand) { cand = iv; ck2 = k; }
        }
      }
    }
    unsigned wi = wave_maxu_bcast(cand);
    if (cand == wi && cand != 0u) {   // unique owner thread in this wave
      float zz = 0.f;
#pragma unroll
      for (int k = 0; k < 32; ++k) if (k == ck2) zz = pz[k];
      float2 xy = s_xy[ck2 * FPS_T + t];
      s_cand[wave][0] = xy.x; s_cand[wave][1] = xy.y; s_cand[wave][2] = zz;
    }
    if (lane == 0) s_ipart[wave] = wi;
    __syncthreads();  // bar2
  }
}

// Gather: out = [ xyz[b][idx[b][s]][c] (B*S*3) , feat[b][idx[b][s]][:] (B*S*C) ]
__global__ void gather_kernel(const float* __restrict__ xyz,
                              const float* __restrict__ feat,
                              const int* __restrict__ idx,
                              float* __restrict__ out,
                              int B, int N, int S, int C) {
  const int c4pr = C >> 2;
  const int nf4 = B * S * c4pr;
  int tid = blockIdx.x * blockDim.x + threadIdx.x;
  if (tid < nf4) {
    int c4 = tid % c4pr;
    int bs = tid / c4pr;
    int s = bs % S, b = bs / S;
    int p = idx[b * S + s];
    const float4* src = (const float4*)(feat + ((size_t)b * N + p) * C);
    float4* dst = (float4*)(out + (size_t)B * S * 3 + ((size_t)bs) * C);
    dst[c4] = src[c4];
  } else {
    int t2 = tid - nf4;
    int nxyz = B * S * 3;
    if (t2 < nxyz) {
      int c = t2 % 3;
      int bs = t2 / 3;
      int s = bs % S, b = bs / S;
      int p = idx[b * S + s];
      out[t2] = xyz[((size_t)b * N + p) * 3 + c];
    }
  }
}

extern "C" void kernel_launch(void* const* d_in, const int* in_sizes, int n_in,
                              void* d_out, int out_size, void* d_ws, size_t ws_size,
                              hipStream_t stream) {
  const float* xyz = (const float*)d_in[0];
  const float* feat = (const float*)d_in[1];
  float* out = (float*)d_out;

  const int B = 32;
  const int N = in_sizes[0] / (B * 3);        // 16384
  const int C = in_sizes[1] / (B * N);        // 128
  const int S = N / 4;                        // 4096

  // ws: idx 512KB | rp 8MB | rbb 24KB
  int* d_idx = (int*)d_ws;
  float4* d_rp = (float4*)((char*)d_ws + (size_t)B * S * sizeof(int));
  float* d_rbb = (float*)((char*)d_rp + (size_t)B * N * sizeof(float4));

  prep_kernel<<<B, PREP_T, 0, stream>>>(xyz, d_rp, d_rbb, N);
  fps_kernel<<<B, FPS_T, 0, stream>>>(xyz, d_rp, d_rbb, d_idx, N, S);

  int total = B * S * (C >> 2) + B * S * 3;
  int blocks = (total + 255) / 256;
  gather_kernel<<<blocks, 256, 0, stream>>>(xyz, feat, d_idx, out, B, N, S, C);
}

// Round 24
// 9173.511 us; speedup vs baseline: 1.5562x; 1.1132x over previous
//
#include <hip/hip_runtime.h>
#include <hip/hip_bf16.h>
#include <cfloat>

// FPS matching the np reference bit-exactly (R7: PASS, absmax 0).
// FROZEN per-point arithmetic: dx=px-cx; y2=dy*dy; inner=fma(dx,dx,y2);
// d=fma(dz,dz,inner); nd=fminf(dist,d); winner=(max value, smallest index).
// R24: R23's lean harness + R22's tight pruning geometry. Chunk = 64
// consecutive cell-sorted points = wave w's lanes at register k (position
// k*512 + w*64 + lane), chunk id c = k*8+w -- wave-private! So chunk boxes
// AND chunk-max both live in registers (lane r of wave w: box+cmax of chunk
// r*8+w). No LDS prune state, no parity, no atomics, no global loads in the
// loop. Argmax always exact over all 32 register ds; inv16 tie-break.

typedef unsigned long long u64;
#define CELLS 512
#define PREP_T 512
#define FPS_T 512
#define NCHUNK 256

template <int CTRL>
__device__ __forceinline__ float dpp_maxf(float v) {
  int iv = __float_as_int(v);
  int sh = __builtin_amdgcn_update_dpp(iv, iv, CTRL, 0xF, 0xF, false);
  return fmaxf(v, __int_as_float(sh));
}
template <int CTRL>
__device__ __forceinline__ unsigned dpp_maxu(unsigned v) {
  int sh = __builtin_amdgcn_update_dpp((int)v, (int)v, CTRL, 0xF, 0xF, false);
  return ((unsigned)sh > v) ? (unsigned)sh : v;
}
// 6-step DPP chain; lane 63 ends with the wave max.
__device__ __forceinline__ float wave_maxf_tail(float v) {
  v = dpp_maxf<0xB1>(v); v = dpp_maxf<0x4E>(v); v = dpp_maxf<0x141>(v);
  v = dpp_maxf<0x140>(v); v = dpp_maxf<0x142>(v); v = dpp_maxf<0x143>(v);
  return v;
}
__device__ __forceinline__ unsigned wave_maxu_bcast(unsigned v) {
  v = dpp_maxu<0xB1>(v); v = dpp_maxu<0x4E>(v); v = dpp_maxu<0x141>(v);
  v = dpp_maxu<0x140>(v); v = dpp_maxu<0x142>(v); v = dpp_maxu<0x143>(v);
  return (unsigned)__builtin_amdgcn_readlane((int)v, 63);
}

__global__ __launch_bounds__(PREP_T) void prep_kernel(
    const float* __restrict__ xyz, float4* __restrict__ rp,
    float* __restrict__ cbb, int N) {
  const int b = blockIdx.x, t = threadIdx.x;
  const float* xb = xyz + (size_t)b * N * 3;
  __shared__ int s_cnt[CELLS], s_start[CELLS], s_off[CELLS];
  __shared__ float s_red[8][6];
  __shared__ float s_bb[6];
  const int PPT = N / PREP_T;
  const int wave = t >> 6, lane = t & 63;

  float mnx = FLT_MAX, mny = FLT_MAX, mnz = FLT_MAX;
  float mxx = -FLT_MAX, mxy = -FLT_MAX, mxz = -FLT_MAX;
  for (int k = 0; k < PPT; ++k) {
    int p = k * PREP_T + t;
    float x = xb[(size_t)p * 3], y = xb[(size_t)p * 3 + 1], z = xb[(size_t)p * 3 + 2];
    mnx = fminf(mnx, x); mny = fminf(mny, y); mnz = fminf(mnz, z);
    mxx = fmaxf(mxx, x); mxy = fmaxf(mxy, y); mxz = fmaxf(mxz, z);
  }
  for (int off = 32; off > 0; off >>= 1) {
    mnx = fminf(mnx, __shfl_xor(mnx, off, 64));
    mny = fminf(mny, __shfl_xor(mny, off, 64));
    mnz = fminf(mnz, __shfl_xor(mnz, off, 64));
    mxx = fmaxf(mxx, __shfl_xor(mxx, off, 64));
    mxy = fmaxf(mxy, __shfl_xor(mxy, off, 64));
    mxz = fmaxf(mxz, __shfl_xor(mxz, off, 64));
  }
  if (lane == 0) {
    s_red[wave][0] = mnx; s_red[wave][1] = mny; s_red[wave][2] = mnz;
    s_red[wave][3] = mxx; s_red[wave][4] = mxy; s_red[wave][5] = mxz;
  }
  __syncthreads();
  if (t == 0) {
    float a = s_red[0][0], bq = s_red[0][1], c = s_red[0][2];
    float d = s_red[0][3], e = s_red[0][4], g = s_red[0][5];
    for (int w = 1; w < 8; ++w) {
      a = fminf(a, s_red[w][0]); bq = fminf(bq, s_red[w][1]); c = fminf(c, s_red[w][2]);
      d = fmaxf(d, s_red[w][3]); e = fmaxf(e, s_red[w][4]); g = fmaxf(g, s_red[w][5]);
    }
    s_bb[0] = a; s_bb[1] = bq; s_bb[2] = c; s_bb[3] = d; s_bb[4] = e; s_bb[5] = g;
  }
  if (t < CELLS) s_cnt[t] = 0;
  __syncthreads();

  float lox = s_bb[0], loy = s_bb[1], loz = s_bb[2];
  float rx = s_bb[3] - lox, ry = s_bb[4] - loy, rz = s_bb[5] - loz;
  float sx = (rx > 0.f) ? 8.f / rx : 0.f;
  float sy = (ry > 0.f) ? 8.f / ry : 0.f;
  float sz = (rz > 0.f) ? 8.f / rz : 0.f;

#define CIDX(v, lo, sc) ({ int cc_ = (int)(((v) - (lo)) * (sc)); cc_ < 0 ? 0 : (cc_ > 7 ? 7 : cc_); })

  for (int k = 0; k < PPT; ++k) {
    int p = k * PREP_T + t;
    float x = xb[(size_t)p * 3], y = xb[(size_t)p * 3 + 1], z = xb[(size_t)p * 3 + 2];
    int cid = (CIDX(x, lox, sx) << 6) | (CIDX(y, loy, sy) << 3) | CIDX(z, loz, sz);
    atomicAdd(&s_cnt[cid], 1);
  }
  __syncthreads();
  if (t < CELLS) s_start[t] = s_cnt[t];
  __syncthreads();
  for (int off = 1; off < CELLS; off <<= 1) {
    int add = 0;
    if (t < CELLS && t >= off) add = s_start[t - off];
    __syncthreads();
    if (t < CELLS) s_start[t] += add;
    __syncthreads();
  }
  if (t < CELLS) { s_start[t] -= s_cnt[t]; s_off[t] = 0; }
  __syncthreads();

  for (int k = 0; k < PPT; ++k) {
    int p = k * PREP_T + t;
    float x = xb[(size_t)p * 3], y = xb[(size_t)p * 3 + 1], z = xb[(size_t)p * 3 + 2];
    int cid = (CIDX(x, lox, sx) << 6) | (CIDX(y, loy, sy) << 3) | CIDX(z, loz, sz);
    int pos = s_start[cid] + atomicAdd(&s_off[cid], 1);
    rp[(size_t)b * N + pos] =
        make_float4(x, y, z, __uint_as_float(0xFFFFFFFFu - (unsigned)p));
  }
  __syncthreads();

  // tight boxes over 64-pt chunks of the sorted order (256 chunks)
  const float4* rpb = rp + (size_t)b * N;
  for (int c = wave; c < NCHUNK; c += PREP_T / 64) {
    float4 q = rpb[c * 64 + lane];
    float a0 = q.x, a1 = q.y, a2 = q.z, a3 = q.x, a4 = q.y, a5 = q.z;
    for (int off = 32; off > 0; off >>= 1) {
      a0 = fminf(a0, __shfl_xor(a0, off, 64));
      a1 = fminf(a1, __shfl_xor(a1, off, 64));
      a2 = fminf(a2, __shfl_xor(a2, off, 64));
      a3 = fmaxf(a3, __shfl_xor(a3, off, 64));
      a4 = fmaxf(a4, __shfl_xor(a4, off, 64));
      a5 = fmaxf(a5, __shfl_xor(a5, off, 64));
    }
    if (lane == 0) {
      float* o = cbb + ((size_t)b * NCHUNK + c) * 6;
      o[0] = a0; o[1] = a1; o[2] = a2; o[3] = a3; o[4] = a4; o[5] = a5;
    }
  }
}

__global__ __launch_bounds__(FPS_T, 2)
void fps_kernel(const float* __restrict__ xyz, const float4* __restrict__ rp,
                const float* __restrict__ cbb, int* __restrict__ out_idx,
                int N, int S) {
#pragma clang fp contract(off)
  const int b = blockIdx.x, t = threadIdx.x;
  const int wave = t >> 6, lane = t & 63;
  const float4* rpb = rp + (size_t)b * N;

  __shared__ float2 s_xy[16384];   // 128 KB
  __shared__ float s_vpart[8];
  __shared__ unsigned s_ipart[8];
  __shared__ float s_cand[8][3];

  float pz[32], ds[32];   // static indexing only
  unsigned ivp[16];       // packed inv16 per pair of rows
#pragma unroll
  for (int k = 0; k < 16; ++k) ivp[k] = 0;
#pragma unroll
  for (int k = 0; k < 32; ++k) {
    float4 q = rpb[(size_t)k * FPS_T + t];
    s_xy[k * FPS_T + t] = make_float2(q.x, q.y);
    pz[k] = q.z;
    ds[k] = FLT_MAX;
    unsigned p = 0xFFFFFFFFu - __float_as_uint(q.w);
    unsigned inv16 = 0xFFFFu - p;
    ivp[k >> 1] |= inv16 << ((k & 1) * 16);
  }
  // lane r (<32) of wave w: box + cmax of chunk r*8+w (register-resident)
  float bx0 = 0, by0 = 0, bz0 = 0, bx1 = 0, by1 = 0, bz1 = 0;
  float cmax = FLT_MAX;
  if (lane < 32) {
    const float* bb = cbb + ((size_t)b * NCHUNK + lane * 8 + wave) * 6;
    bx0 = bb[0]; by0 = bb[1]; bz0 = bb[2];
    bx1 = bb[3]; by1 = bb[4]; bz1 = bb[5];
  }
  if (t < 8) s_ipart[t] = (t == 0) ? 0xFFFFu : 0u;  // inv16 of p=0
  if (t == 0) {
    s_cand[0][0] = xyz[(size_t)b * N * 3 + 0];
    s_cand[0][1] = xyz[(size_t)b * N * 3 + 1];
    s_cand[0][2] = xyz[(size_t)b * N * 3 + 2];
  }
  __syncthreads();

  for (int s = 0; s < S; ++s) {
    // resolve previous winner
    unsigned ginv = s_ipart[0];
    int wstar = 0;
#pragma unroll
    for (int w = 1; w < 8; ++w) {
      unsigned v = s_ipart[w];
      if (v > ginv) { ginv = v; wstar = w; }
    }
    if (t == 0) out_idx[(size_t)b * S + s] = (int)(0xFFFFu - ginv);
    float cx = s_cand[wstar][0], cy = s_cand[wstar][1], cz = s_cand[wstar][2];

    // skip test: lane k handles chunk k*8+wave (box + cmax in registers)
    bool act = false;
    if (lane < 32) {
      float gx = fmaxf(0.f, fmaxf(bx0 - cx, cx - bx1));
      float gy = fmaxf(0.f, fmaxf(by0 - cy, cy - by1));
      float gz = fmaxf(0.f, fmaxf(bz0 - cz, cz - bz1));
      float bound = gx * gx + gy * gy + gz * gz;
      act = (bound * 0.999f <= cmax);
    }
    unsigned mask = (unsigned)__ballot(act);

    // scan active chunks: FROZEN chain; update register cmax at lane k
#pragma unroll
    for (int k = 0; k < 32; ++k) {
      if (mask & (1u << k)) {
        float2 xy = s_xy[k * FPS_T + t];
        float dx = xy.x - cx, dy = xy.y - cy, dz = pz[k] - cz;
        float y2 = dy * dy;
        float inner = __builtin_fmaf(dx, dx, y2);
        float dd = __builtin_fmaf(dz, dz, inner);
        float nd = fminf(ds[k], dd);
        ds[k] = nd;
        float rm = wave_maxf_tail(nd);
        float cmn = __int_as_float(__builtin_amdgcn_readlane(__float_as_int(rm), 63));
        if (lane == k) cmax = cmn;
      }
    }

    // exact per-thread argmax over all 32 ds (tree; independent of pruning)
    float m16[16];
#pragma unroll
    for (int i = 0; i < 16; ++i) m16[i] = fmaxf(ds[i], ds[i + 16]);
#pragma unroll
    for (int i = 0; i < 8; ++i) m16[i] = fmaxf(m16[i], m16[i + 8]);
#pragma unroll
    for (int i = 0; i < 4; ++i) m16[i] = fmaxf(m16[i], m16[i + 4]);
    float bestv = fmaxf(fmaxf(m16[0], m16[1]), fmaxf(m16[2], m16[3]));
    float wv = wave_maxf_tail(bestv);
    if (lane == 63) s_vpart[wave] = wv;
    __syncthreads();  // bar1

    float vstar = s_vpart[0];
#pragma unroll
    for (int w = 1; w < 8; ++w) vstar = fmaxf(vstar, s_vpart[w]);

    // tie-resolve: max inv16 (= min orig p) among ds == vstar
    unsigned cand = 0;
    int ck2 = 0;
    if (bestv == vstar) {
#pragma unroll
      for (int k = 0; k < 32; ++k) {
        if (ds[k] == vstar) {
          unsigned iv = (ivp[k >> 1] >> ((k & 1) * 16)) & 0xFFFFu;
          if (iv > cand) { cand = iv; ck2 = k; }
        }
      }
    }
    unsigned wi = wave_maxu_bcast(cand);
    if (cand == wi && cand != 0u) {   // unique owner thread in this wave
      float zz = 0.f;
#pragma unroll
      for (int k = 0; k < 32; ++k) if (k == ck2) zz = pz[k];
      float2 xy = s_xy[ck2 * FPS_T + t];
      s_cand[wave][0] = xy.x; s_cand[wave][1] = xy.y; s_cand[wave][2] = zz;
    }
    if (lane == 0) s_ipart[wave] = wi;
    __syncthreads();  // bar2
  }
}

// Gather: out = [ xyz[b][idx[b][s]][c] (B*S*3) , feat[b][idx[b][s]][:] (B*S*C) ]
__global__ void gather_kernel(const float* __restrict__ xyz,
                              const float* __restrict__ feat,
                              const int* __restrict__ idx,
                              float* __restrict__ out,
                              int B, int N, int S, int C) {
  const int c4pr = C >> 2;
  const int nf4 = B * S * c4pr;
  int tid = blockIdx.x * blockDim.x + threadIdx.x;
  if (tid < nf4) {
    int c4 = tid % c4pr;
    int bs = tid / c4pr;
    int s = bs % S, b = bs / S;
    int p = idx[b * S + s];
    const float4* src = (const float4*)(feat + ((size_t)b * N + p) * C);
    float4* dst = (float4*)(out + (size_t)B * S * 3 + ((size_t)bs) * C);
    dst[c4] = src[c4];
  } else {
    int t2 = tid - nf4;
    int nxyz = B * S * 3;
    if (t2 < nxyz) {
      int c = t2 % 3;
      int bs = t2 / 3;
      int s = bs % S, b = bs / S;
      int p = idx[b * S + s];
      out[t2] = xyz[((size_t)b * N + p) * 3 + c];
    }
  }
}

extern "C" void kernel_launch(void* const* d_in, const int* in_sizes, int n_in,
                              void* d_out, int out_size, void* d_ws, size_t ws_size,
                              hipStream_t stream) {
  const float* xyz = (const float*)d_in[0];
  const float* feat = (const float*)d_in[1];
  float* out = (float*)d_out;

  const int B = 32;
  const int N = in_sizes[0] / (B * 3);        // 16384
  const int C = in_sizes[1] / (B * N);        // 128
  const int S = N / 4;                        // 4096

  // ws: idx 512KB | rp 8MB | cbb 196KB
  int* d_idx = (int*)d_ws;
  float4* d_rp = (float4*)((char*)d_ws + (size_t)B * S * sizeof(int));
  float* d_cbb = (float*)((char*)d_rp + (size_t)B * N * sizeof(float4));

  prep_kernel<<<B, PREP_T, 0, stream>>>(xyz, d_rp, d_cbb, N);
  fps_kernel<<<B, FPS_T, 0, stream>>>(xyz, d_rp, d_cbb, d_idx, N, S);

  int total = B * S * (C >> 2) + B * S * 3;
  int blocks = (total + 255) / 256;
  gather_kernel<<<blocks, 256, 0, stream>>>(xyz, feat, d_idx, out, B, N, S, C);
}

// Round 25
// 8107.062 us; speedup vs baseline: 1.7609x; 1.1315x over previous
//
#include <hip/hip_runtime.h>
#include <hip/hip_bf16.h>
#include <cfloat>

// FPS matching the np reference bit-exactly (R7: PASS, absmax 0).
// FROZEN per-point arithmetic: dx=px-cx; y2=dy*dy; inner=fma(dx,dx,y2);
// d=fma(dz,dz,inner); nd=fminf(dist,d); winner=(max value, smallest index).
// R25: R24 minus ALL per-chunk prune maintenance. dist is monotone
// decreasing => every chunk's max <= vstar_prev (last step's global max,
// already computed for the argmax). Skip iff bound*0.999 > vstar_prev --
// strictly more conservative than R24's per-chunk test (validated 3x,
// absmax 0). Deletes the per-active-chunk DPP chains/readlane/cndmask
// (~150-250cy serial each) that dominated R24's 5375 cy/step.

typedef unsigned long long u64;
#define CELLS 512
#define PREP_T 512
#define FPS_T 512
#define NCHUNK 256

template <int CTRL>
__device__ __forceinline__ float dpp_maxf(float v) {
  int iv = __float_as_int(v);
  int sh = __builtin_amdgcn_update_dpp(iv, iv, CTRL, 0xF, 0xF, false);
  return fmaxf(v, __int_as_float(sh));
}
template <int CTRL>
__device__ __forceinline__ unsigned dpp_maxu(unsigned v) {
  int sh = __builtin_amdgcn_update_dpp((int)v, (int)v, CTRL, 0xF, 0xF, false);
  return ((unsigned)sh > v) ? (unsigned)sh : v;
}
// 6-step DPP chain; lane 63 ends with the wave max.
__device__ __forceinline__ float wave_maxf_tail(float v) {
  v = dpp_maxf<0xB1>(v); v = dpp_maxf<0x4E>(v); v = dpp_maxf<0x141>(v);
  v = dpp_maxf<0x140>(v); v = dpp_maxf<0x142>(v); v = dpp_maxf<0x143>(v);
  return v;
}
__device__ __forceinline__ unsigned wave_maxu_bcast(unsigned v) {
  v = dpp_maxu<0xB1>(v); v = dpp_maxu<0x4E>(v); v = dpp_maxu<0x141>(v);
  v = dpp_maxu<0x140>(v); v = dpp_maxu<0x142>(v); v = dpp_maxu<0x143>(v);
  return (unsigned)__builtin_amdgcn_readlane((int)v, 63);
}

__global__ __launch_bounds__(PREP_T) void prep_kernel(
    const float* __restrict__ xyz, float4* __restrict__ rp,
    float* __restrict__ cbb, int N) {
  const int b = blockIdx.x, t = threadIdx.x;
  const float* xb = xyz + (size_t)b * N * 3;
  __shared__ int s_cnt[CELLS], s_start[CELLS], s_off[CELLS];
  __shared__ float s_red[8][6];
  __shared__ float s_bb[6];
  const int PPT = N / PREP_T;
  const int wave = t >> 6, lane = t & 63;

  float mnx = FLT_MAX, mny = FLT_MAX, mnz = FLT_MAX;
  float mxx = -FLT_MAX, mxy = -FLT_MAX, mxz = -FLT_MAX;
  for (int k = 0; k < PPT; ++k) {
    int p = k * PREP_T + t;
    float x = xb[(size_t)p * 3], y = xb[(size_t)p * 3 + 1], z = xb[(size_t)p * 3 + 2];
    mnx = fminf(mnx, x); mny = fminf(mny, y); mnz = fminf(mnz, z);
    mxx = fmaxf(mxx, x); mxy = fmaxf(mxy, y); mxz = fmaxf(mxz, z);
  }
  for (int off = 32; off > 0; off >>= 1) {
    mnx = fminf(mnx, __shfl_xor(mnx, off, 64));
    mny = fminf(mny, __shfl_xor(mny, off, 64));
    mnz = fminf(mnz, __shfl_xor(mnz, off, 64));
    mxx = fmaxf(mxx, __shfl_xor(mxx, off, 64));
    mxy = fmaxf(mxy, __shfl_xor(mxy, off, 64));
    mxz = fmaxf(mxz, __shfl_xor(mxz, off, 64));
  }
  if (lane == 0) {
    s_red[wave][0] = mnx; s_red[wave][1] = mny; s_red[wave][2] = mnz;
    s_red[wave][3] = mxx; s_red[wave][4] = mxy; s_red[wave][5] = mxz;
  }
  __syncthreads();
  if (t == 0) {
    float a = s_red[0][0], bq = s_red[0][1], c = s_red[0][2];
    float d = s_red[0][3], e = s_red[0][4], g = s_red[0][5];
    for (int w = 1; w < 8; ++w) {
      a = fminf(a, s_red[w][0]); bq = fminf(bq, s_red[w][1]); c = fminf(c, s_red[w][2]);
      d = fmaxf(d, s_red[w][3]); e = fmaxf(e, s_red[w][4]); g = fmaxf(g, s_red[w][5]);
    }
    s_bb[0] = a; s_bb[1] = bq; s_bb[2] = c; s_bb[3] = d; s_bb[4] = e; s_bb[5] = g;
  }
  if (t < CELLS) s_cnt[t] = 0;
  __syncthreads();

  float lox = s_bb[0], loy = s_bb[1], loz = s_bb[2];
  float rx = s_bb[3] - lox, ry = s_bb[4] - loy, rz = s_bb[5] - loz;
  float sx = (rx > 0.f) ? 8.f / rx : 0.f;
  float sy = (ry > 0.f) ? 8.f / ry : 0.f;
  float sz = (rz > 0.f) ? 8.f / rz : 0.f;

#define CIDX(v, lo, sc) ({ int cc_ = (int)(((v) - (lo)) * (sc)); cc_ < 0 ? 0 : (cc_ > 7 ? 7 : cc_); })

  for (int k = 0; k < PPT; ++k) {
    int p = k * PREP_T + t;
    float x = xb[(size_t)p * 3], y = xb[(size_t)p * 3 + 1], z = xb[(size_t)p * 3 + 2];
    int cid = (CIDX(x, lox, sx) << 6) | (CIDX(y, loy, sy) << 3) | CIDX(z, loz, sz);
    atomicAdd(&s_cnt[cid], 1);
  }
  __syncthreads();
  if (t < CELLS) s_start[t] = s_cnt[t];
  __syncthreads();
  for (int off = 1; off < CELLS; off <<= 1) {
    int add = 0;
    if (t < CELLS && t >= off) add = s_start[t - off];
    __syncthreads();
    if (t < CELLS) s_start[t] += add;
    __syncthreads();
  }
  if (t < CELLS) { s_start[t] -= s_cnt[t]; s_off[t] = 0; }
  __syncthreads();

  for (int k = 0; k < PPT; ++k) {
    int p = k * PREP_T + t;
    float x = xb[(size_t)p * 3], y = xb[(size_t)p * 3 + 1], z = xb[(size_t)p * 3 + 2];
    int cid = (CIDX(x, lox, sx) << 6) | (CIDX(y, loy, sy) << 3) | CIDX(z, loz, sz);
    int pos = s_start[cid] + atomicAdd(&s_off[cid], 1);
    rp[(size_t)b * N + pos] =
        make_float4(x, y, z, __uint_as_float(0xFFFFFFFFu - (unsigned)p));
  }
  __syncthreads();

  // tight boxes over 64-pt chunks of the sorted order (256 chunks)
  const float4* rpb = rp + (size_t)b * N;
  for (int c = wave; c < NCHUNK; c += PREP_T / 64) {
    float4 q = rpb[c * 64 + lane];
    float a0 = q.x, a1 = q.y, a2 = q.z, a3 = q.x, a4 = q.y, a5 = q.z;
    for (int off = 32; off > 0; off >>= 1) {
      a0 = fminf(a0, __shfl_xor(a0, off, 64));
      a1 = fminf(a1, __shfl_xor(a1, off, 64));
      a2 = fminf(a2, __shfl_xor(a2, off, 64));
      a3 = fmaxf(a3, __shfl_xor(a3, off, 64));
      a4 = fmaxf(a4, __shfl_xor(a4, off, 64));
      a5 = fmaxf(a5, __shfl_xor(a5, off, 64));
    }
    if (lane == 0) {
      float* o = cbb + ((size_t)b * NCHUNK + c) * 6;
      o[0] = a0; o[1] = a1; o[2] = a2; o[3] = a3; o[4] = a4; o[5] = a5;
    }
  }
}

__global__ __launch_bounds__(FPS_T, 2)
void fps_kernel(const float* __restrict__ xyz, const float4* __restrict__ rp,
                const float* __restrict__ cbb, int* __restrict__ out_idx,
                int N, int S) {
#pragma clang fp contract(off)
  const int b = blockIdx.x, t = threadIdx.x;
  const int wave = t >> 6, lane = t & 63;
  const float4* rpb = rp + (size_t)b * N;

  __shared__ float2 s_xy[16384];   // 128 KB
  __shared__ float s_vpart[8];
  __shared__ unsigned s_ipart[8];
  __shared__ float s_cand[8][3];

  float pz[32], ds[32];   // static indexing only
  unsigned ivp[16];       // packed inv16 per pair of rows
#pragma unroll
  for (int k = 0; k < 16; ++k) ivp[k] = 0;
#pragma unroll
  for (int k = 0; k < 32; ++k) {
    float4 q = rpb[(size_t)k * FPS_T + t];
    s_xy[k * FPS_T + t] = make_float2(q.x, q.y);
    pz[k] = q.z;
    ds[k] = FLT_MAX;
    unsigned p = 0xFFFFFFFFu - __float_as_uint(q.w);
    unsigned inv16 = 0xFFFFu - p;
    ivp[k >> 1] |= inv16 << ((k & 1) * 16);
  }
  // lane r (<32) of wave w: box of chunk r*8+w (register-resident)
  float bx0 = 0, by0 = 0, bz0 = 0, bx1 = 0, by1 = 0, bz1 = 0;
  if (lane < 32) {
    const float* bb = cbb + ((size_t)b * NCHUNK + lane * 8 + wave) * 6;
    bx0 = bb[0]; by0 = bb[1]; bz0 = bb[2];
    bx1 = bb[3]; by1 = bb[4]; bz1 = bb[5];
  }
  if (t < 8) s_ipart[t] = (t == 0) ? 0xFFFFu : 0u;  // inv16 of p=0
  if (t == 0) {
    s_cand[0][0] = xyz[(size_t)b * N * 3 + 0];
    s_cand[0][1] = xyz[(size_t)b * N * 3 + 1];
    s_cand[0][2] = xyz[(size_t)b * N * 3 + 2];
  }
  float vstar_prev = FLT_MAX;   // global max dist after previous step
  __syncthreads();

  for (int s = 0; s < S; ++s) {
    // resolve previous winner
    unsigned ginv = s_ipart[0];
    int wstar = 0;
#pragma unroll
    for (int w = 1; w < 8; ++w) {
      unsigned v = s_ipart[w];
      if (v > ginv) { ginv = v; wstar = w; }
    }
    if (t == 0) out_idx[(size_t)b * S + s] = (int)(0xFFFFu - ginv);
    float cx = s_cand[wstar][0], cy = s_cand[wstar][1], cz = s_cand[wstar][2];

    // skip test vs GLOBAL bound: cmax_chunk <= vstar_prev always
    bool act = false;
    if (lane < 32) {
      float gx = fmaxf(0.f, fmaxf(bx0 - cx, cx - bx1));
      float gy = fmaxf(0.f, fmaxf(by0 - cy, cy - by1));
      float gz = fmaxf(0.f, fmaxf(bz0 - cz, cz - bz1));
      float bound = gx * gx + gy * gy + gz * gz;
      act = (bound * 0.999f <= vstar_prev);
    }
    unsigned mask = (unsigned)__ballot(act);

    // scan active chunks: FROZEN chain only (no prune maintenance)
#pragma unroll
    for (int k = 0; k < 32; ++k) {
      if (mask & (1u << k)) {
        float2 xy = s_xy[k * FPS_T + t];
        float dx = xy.x - cx, dy = xy.y - cy, dz = pz[k] - cz;
        float y2 = dy * dy;
        float inner = __builtin_fmaf(dx, dx, y2);
        float dd = __builtin_fmaf(dz, dz, inner);
        ds[k] = fminf(ds[k], dd);
      }
    }

    // exact per-thread argmax over all 32 ds (tree; independent of pruning)
    float m16[16];
#pragma unroll
    for (int i = 0; i < 16; ++i) m16[i] = fmaxf(ds[i], ds[i + 16]);
#pragma unroll
    for (int i = 0; i < 8; ++i) m16[i] = fmaxf(m16[i], m16[i + 8]);
#pragma unroll
    for (int i = 0; i < 4; ++i) m16[i] = fmaxf(m16[i], m16[i + 4]);
    float bestv = fmaxf(fmaxf(m16[0], m16[1]), fmaxf(m16[2], m16[3]));
    float wv = wave_maxf_tail(bestv);
    if (lane == 63) s_vpart[wave] = wv;
    __syncthreads();  // bar1

    float vstar = s_vpart[0];
#pragma unroll
    for (int w = 1; w < 8; ++w) vstar = fmaxf(vstar, s_vpart[w]);
    vstar_prev = vstar;   // bound for the next step

    // tie-resolve: max inv16 (= min orig p) among ds == vstar
    unsigned cand = 0;
    int ck2 = 0;
    if (bestv == vstar) {
#pragma unroll
      for (int k = 0; k < 32; ++k) {
        if (ds[k] == vstar) {
          unsigned iv = (ivp[k >> 1] >> ((k & 1) * 16)) & 0xFFFFu;
          if (iv > cand) { cand = iv; ck2 = k; }
        }
      }
    }
    unsigned wi = wave_maxu_bcast(cand);
    if (cand == wi && cand != 0u) {   // unique owner thread in this wave
      float zz = 0.f;
#pragma unroll
      for (int k = 0; k < 32; ++k) if (k == ck2) zz = pz[k];
      float2 xy = s_xy[ck2 * FPS_T + t];
      s_cand[wave][0] = xy.x; s_cand[wave][1] = xy.y; s_cand[wave][2] = zz;
    }
    if (lane == 0) s_ipart[wave] = wi;
    __syncthreads();  // bar2
  }
}

// Gather: out = [ xyz[b][idx[b][s]][c] (B*S*3) , feat[b][idx[b][s]][:] (B*S*C) ]
__global__ void gather_kernel(const float* __restrict__ xyz,
                              const float* __restrict__ feat,
                              const int* __restrict__ idx,
                              float* __restrict__ out,
                              int B, int N, int S, int C) {
  const int c4pr = C >> 2;
  const int nf4 = B * S * c4pr;
  int tid = blockIdx.x * blockDim.x + threadIdx.x;
  if (tid < nf4) {
    int c4 = tid % c4pr;
    int bs = tid / c4pr;
    int s = bs % S, b = bs / S;
    int p = idx[b * S + s];
    const float4* src = (const float4*)(feat + ((size_t)b * N + p) * C);
    float4* dst = (float4*)(out + (size_t)B * S * 3 + ((size_t)bs) * C);
    dst[c4] = src[c4];
  } else {
    int t2 = tid - nf4;
    int nxyz = B * S * 3;
    if (t2 < nxyz) {
      int c = t2 % 3;
      int bs = t2 / 3;
      int s = bs % S, b = bs / S;
      int p = idx[b * S + s];
      out[t2] = xyz[((size_t)b * N + p) * 3 + c];
    }
  }
}

extern "C" void kernel_launch(void* const* d_in, const int* in_sizes, int n_in,
                              void* d_out, int out_size, void* d_ws, size_t ws_size,
                              hipStream_t stream) {
  const float* xyz = (const float*)d_in[0];
  const float* feat = (const float*)d_in[1];
  float* out = (float*)d_out;

  const int B = 32;
  const int N = in_sizes[0] / (B * 3);        // 16384
  const int C = in_sizes[1] / (B * N);        // 128
  const int S = N / 4;                        // 4096

  // ws: idx 512KB | rp 8MB | cbb 196KB
  int* d_idx = (int*)d_ws;
  float4* d_rp = (float4*)((char*)d_ws + (size_t)B * S * sizeof(int));
  float* d_cbb = (float*)((char*)d_rp + (size_t)B * N * sizeof(float4));

  prep_kernel<<<B, PREP_T, 0, stream>>>(xyz, d_rp, d_cbb, N);
  fps_kernel<<<B, FPS_T, 0, stream>>>(xyz, d_rp, d_cbb, d_idx, N, S);

  int total = B * S * (C >> 2) + B * S * 3;
  int blocks = (total + 255) / 256;
  gather_kernel<<<blocks, 256, 0, stream>>>(xyz, feat, d_idx, out, B, N, S, C);
}

// Round 26
// 6385.480 us; speedup vs baseline: 2.2356x; 1.2696x over previous
//
#include <hip/hip_runtime.h>
#include <hip/hip_bf16.h>
#include <cfloat>

// FPS matching the np reference bit-exactly (R7: PASS, absmax 0).
// FROZEN per-point arithmetic: dx=px-cx; y2=dy*dy; inner=fma(dx,dx,y2);
// d=fma(dz,dz,inner); nd=fminf(dist,d); winner=(max value, smallest index).
// R26: pruning family closed (R21-R25 all worse than R19's full scan -- the
// exact argmax's block-wide reduce backbone dominates). Last untested axis:
// R19's structure at 1024 threads. Prior 1024-thr failures were fat-state
// VGPR spills; R19's state at 1024thr is only ~16 floats/thread -> fits.
// 16 waves (4/SIMD) pipeline the 128KB LDS + 64KB global-z scan streams.

typedef unsigned long long u64;
#define FPS_THREADS 1024
#define TR_T 512

#define REP8(M) M(0) M(1) M(2) M(3) M(4) M(5) M(6) M(7)

template <int CTRL>
__device__ __forceinline__ float dpp_maxf(float v) {
  int iv = __float_as_int(v);
  int sh = __builtin_amdgcn_update_dpp(iv, iv, CTRL, 0xF, 0xF, false);
  return fmaxf(v, __int_as_float(sh));
}
template <int CTRL>
__device__ __forceinline__ unsigned dpp_maxu(unsigned v) {
  int sh = __builtin_amdgcn_update_dpp((int)v, (int)v, CTRL, 0xF, 0xF, false);
  return ((unsigned)sh > v) ? (unsigned)sh : v;
}
__device__ __forceinline__ float wave_maxf(float v) {
  v = dpp_maxf<0xB1>(v);   // quad_perm xor1
  v = dpp_maxf<0x4E>(v);   // quad_perm xor2
  v = dpp_maxf<0x141>(v);  // row_half_mirror
  v = dpp_maxf<0x140>(v);  // row_mirror
  v = dpp_maxf<0x142>(v);  // row_bcast15
  v = dpp_maxf<0x143>(v);  // row_bcast31 -> lane63 has max
  return __int_as_float(__builtin_amdgcn_readlane(__float_as_int(v), 63));
}
__device__ __forceinline__ unsigned wave_maxu(unsigned v) {
  v = dpp_maxu<0xB1>(v);
  v = dpp_maxu<0x4E>(v);
  v = dpp_maxu<0x141>(v);
  v = dpp_maxu<0x140>(v);
  v = dpp_maxu<0x142>(v);
  v = dpp_maxu<0x143>(v);
  return (unsigned)__builtin_amdgcn_readlane((int)v, 63);
}

__global__ __launch_bounds__(TR_T) void transpose_kernel(
    const float* __restrict__ xyz, float2* __restrict__ xyp,
    float* __restrict__ zp, int N) {
  const int b = blockIdx.x;
  const int t = threadIdx.x;
  const float* xb = xyz + (size_t)b * N * 3;
  float2* xyb = xyp + (size_t)b * N;
  float* zb = zp + (size_t)b * N;
#pragma unroll
  for (int k = 0; k < 32; ++k) {
    int p = k * TR_T + t;
    xyb[p] = make_float2(xb[(size_t)p * 3 + 0], xb[(size_t)p * 3 + 1]);
    zb[p] = xb[(size_t)p * 3 + 2];
  }
}

__global__ __launch_bounds__(FPS_THREADS, 4)
void fps_kernel(const float2* __restrict__ xyp, const float* __restrict__ zp,
                int* __restrict__ out_idx, int N, int S) {
#pragma clang fp contract(off)
  const int b = blockIdx.x;
  const int t = threadIdx.x;
  const int wave = t >> 6, lane = t & 63;
  const float4* xyb4 = (const float4*)(xyp + (size_t)b * N);  // [x0 y0 x1 y1]
  const float2* zb2 = (const float2*)(zp + (size_t)b * N);    // [z0 z1]
  const float* zb = zp + (size_t)b * N;

  __shared__ float4 s_xy4[8192];   // 128 KB: entry e <-> points 2e, 2e+1
  __shared__ u64 s_k[2][16];

  // dist for points p0 = k*2048 + 2t, p1 = p0+1, k = 0..7
#define DECLP(k) float dsA##k, dsB##k;
  REP8(DECLP)

#define LOADP(k) { int e = (k) * FPS_THREADS + t;  \
    s_xy4[e] = xyb4[e];                            \
    dsA##k = FLT_MAX; dsB##k = FLT_MAX; }
  REP8(LOADP)

  const unsigned invt2 = 0xFFFFFFFFu - (unsigned)(2 * t);
  int farthest = 0;

  __syncthreads();  // s_xy4 visible

  for (int s = 0; s < S; ++s) {
    if (t == 0) out_idx[(size_t)b * S + s] = farthest;

    // centroid: entry f>>1, element f&1; z from dense plane (consumed last)
    int f = __builtin_amdgcn_readfirstlane(farthest);
    float cz = zb[f];
    float4 cq = s_xy4[f >> 1];
    int j = f & 1;
    float cx = j ? cq.z : cq.x;
    float cy = j ? cq.w : cq.y;

    float bestv = -1.0f;
    int bestk = 0, bestj = 0;   // inline-constant cndmask candidates

    // FROZEN reference arithmetic; scan ascending orig index (k asc, p0 then p1)
#define STEPP(k) {                                               \
    int e = (k) * FPS_THREADS + t;                               \
    float4 q = s_xy4[e];                                         \
    float2 z2 = zb2[e];                                          \
    { float dx = q.x - cx, dy = q.y - cy, dz = z2.x - cz;        \
      float y2 = dy * dy;                                        \
      float inner = __builtin_fmaf(dx, dx, y2);                  \
      float dd = __builtin_fmaf(dz, dz, inner);                  \
      float nd = fminf(dsA##k, dd);                              \
      dsA##k = nd;                                               \
      if (nd > bestv) { bestv = nd; bestk = (k); bestj = 0; } }  \
    { float dx = q.z - cx, dy = q.w - cy, dz = z2.y - cz;        \
      float y2 = dy * dy;                                        \
      float inner = __builtin_fmaf(dx, dx, y2);                  \
      float dd = __builtin_fmaf(dz, dz, inner);                  \
      float nd = fminf(dsB##k, dd);                              \
      dsB##k = nd;                                               \
      if (nd > bestv) { bestv = nd; bestk = (k); bestj = 1; } } }
    REP8(STEPP)

    // inv original index: orig = bestk*2048 + 2t + bestj
    unsigned bestinv = invt2 - (unsigned)((bestk << 11) + bestj);

    // wave reduce via DPP: max value, then max inv among ties (exact
    // first-occurrence: max inv == min orig index)
    float wmax = wave_maxf(bestv);
    unsigned cand = (bestv == wmax) ? bestinv : 0u;
    unsigned winv = wave_maxu(cand);

    // single barrier per step: parity double-buffer
    const int par = s & 1;
    if (lane == 0)
      s_k[par][wave] = ((u64)__float_as_uint(wmax) << 32) | (u64)winv;
    __syncthreads();

    // cross-wave: 16 keys -> per-lane slot + 4-level butterfly
    u64 bk = s_k[par][lane & 15];
#pragma unroll
    for (int off = 8; off > 0; off >>= 1) {
      u64 ok = __shfl_xor(bk, off, 64);
      if (ok > bk) bk = ok;
    }
    farthest = (int)(0xFFFFFFFFu - (unsigned)(bk & 0xFFFFFFFFu));
  }
}

// Gather: out = [ xyz[b][idx[b][s]][c] (B*S*3) , feat[b][idx[b][s]][:] (B*S*C) ]
__global__ void gather_kernel(const float* __restrict__ xyz,
                              const float* __restrict__ feat,
                              const int* __restrict__ idx,
                              float* __restrict__ out,
                              int B, int N, int S, int C) {
  const int c4pr = C >> 2;
  const int nf4 = B * S * c4pr;
  int tid = blockIdx.x * blockDim.x + threadIdx.x;
  if (tid < nf4) {
    int c4 = tid % c4pr;
    int bs = tid / c4pr;
    int s = bs % S, b = bs / S;
    int p = idx[b * S + s];
    const float4* src = (const float4*)(feat + ((size_t)b * N + p) * C);
    float4* dst = (float4*)(out + (size_t)B * S * 3 + ((size_t)bs) * C);
    dst[c4] = src[c4];
  } else {
    int t2 = tid - nf4;
    int nxyz = B * S * 3;
    if (t2 < nxyz) {
      int c = t2 % 3;
      int bs = t2 / 3;
      int s = bs % S, b = bs / S;
      int p = idx[b * S + s];
      out[t2] = xyz[((size_t)b * N + p) * 3 + c];
    }
  }
}

extern "C" void kernel_launch(void* const* d_in, const int* in_sizes, int n_in,
                              void* d_out, int out_size, void* d_ws, size_t ws_size,
                              hipStream_t stream) {
  const float* xyz = (const float*)d_in[0];
  const float* feat = (const float*)d_in[1];
  float* out = (float*)d_out;

  const int B = 32;
  const int N = in_sizes[0] / (B * 3);        // 16384
  const int C = in_sizes[1] / (B * N);        // 128
  const int S = N / 4;                        // 4096

  // ws: idx 512KB | xy planes (4MB, 16B-aligned) | z (2MB)
  int* d_idx = (int*)d_ws;
  float2* d_xy = (float2*)((char*)d_ws + (size_t)B * S * sizeof(int));
  float* d_z = (float*)((char*)d_xy + (size_t)B * N * sizeof(float2));

  transpose_kernel<<<B, TR_T, 0, stream>>>(xyz, d_xy, d_z, N);
  fps_kernel<<<B, FPS_THREADS, 0, stream>>>(d_xy, d_z, d_idx, N, S);

  int total = B * S * (C >> 2) + B * S * 3;
  int blocks = (total + 255) / 256;
  gather_kernel<<<blocks, 256, 0, stream>>>(xyz, feat, d_idx, out, B, N, S, C);
}

// Round 27
// 5693.743 us; speedup vs baseline: 2.5072x; 1.1215x over previous
//
#include <hip/hip_runtime.h>
#include <hip/hip_bf16.h>
#include <cfloat>

// FPS matching the np reference bit-exactly (R7: PASS, absmax 0).
// FROZEN per-point arithmetic: dx=px-cx; y2=dy*dy; inner=fma(dx,dx,y2);
// d=fma(dz,dz,inner); nd=fminf(dist,d); winner=(max value, smallest index).
// FINAL (R19 structure, best of 26 rounds: 5697us): full-scan split across
// pipes -- xy in LDS via ds_read_b128 (the only efficient LDS width) + z
// dense global (VMEM pipe), DPP wave reduction (VALU pipe), u64 key
// tie-break, 1 barrier/step. FPS is 4096 strictly serial steps; batch=32
// caps usable CUs at 32; per-step 192KB/CU state stream is the floor.

typedef unsigned long long u64;
#define FPS_THREADS 512

#define REP16(M) M(0) M(1) M(2) M(3) M(4) M(5) M(6) M(7) \
                 M(8) M(9) M(10) M(11) M(12) M(13) M(14) M(15)

template <int CTRL>
__device__ __forceinline__ float dpp_maxf(float v) {
  int iv = __float_as_int(v);
  int sh = __builtin_amdgcn_update_dpp(iv, iv, CTRL, 0xF, 0xF, false);
  return fmaxf(v, __int_as_float(sh));
}
template <int CTRL>
__device__ __forceinline__ unsigned dpp_maxu(unsigned v) {
  int sh = __builtin_amdgcn_update_dpp((int)v, (int)v, CTRL, 0xF, 0xF, false);
  return ((unsigned)sh > v) ? (unsigned)sh : v;
}
__device__ __forceinline__ float wave_maxf(float v) {
  v = dpp_maxf<0xB1>(v);   // quad_perm xor1
  v = dpp_maxf<0x4E>(v);   // quad_perm xor2
  v = dpp_maxf<0x141>(v);  // row_half_mirror (xor4)
  v = dpp_maxf<0x140>(v);  // row_mirror (xor8)
  v = dpp_maxf<0x142>(v);  // row_bcast15
  v = dpp_maxf<0x143>(v);  // row_bcast31 -> lane63 has max
  return __int_as_float(__builtin_amdgcn_readlane(__float_as_int(v), 63));
}
__device__ __forceinline__ unsigned wave_maxu(unsigned v) {
  v = dpp_maxu<0xB1>(v);
  v = dpp_maxu<0x4E>(v);
  v = dpp_maxu<0x141>(v);
  v = dpp_maxu<0x140>(v);
  v = dpp_maxu<0x142>(v);
  v = dpp_maxu<0x143>(v);
  return (unsigned)__builtin_amdgcn_readlane((int)v, 63);
}

__global__ __launch_bounds__(FPS_THREADS) void transpose_kernel(
    const float* __restrict__ xyz, float2* __restrict__ xyp,
    float* __restrict__ zp, int N) {
  const int b = blockIdx.x;
  const int t = threadIdx.x;
  const float* xb = xyz + (size_t)b * N * 3;
  float2* xyb = xyp + (size_t)b * N;
  float* zb = zp + (size_t)b * N;
#pragma unroll
  for (int k = 0; k < 32; ++k) {
    int p = k * FPS_THREADS + t;
    xyb[p] = make_float2(xb[(size_t)p * 3 + 0], xb[(size_t)p * 3 + 1]);
    zb[p] = xb[(size_t)p * 3 + 2];
  }
}

__global__ __launch_bounds__(FPS_THREADS, 2)
void fps_kernel(const float2* __restrict__ xyp, const float* __restrict__ zp,
                int* __restrict__ out_idx, int N, int S) {
#pragma clang fp contract(off)
  const int b = blockIdx.x;
  const int t = threadIdx.x;
  const float4* xyb4 = (const float4*)(xyp + (size_t)b * N);  // [x0 y0 x1 y1]
  const float2* zb2 = (const float2*)(zp + (size_t)b * N);    // [z0 z1]
  const float* zb = zp + (size_t)b * N;

  __shared__ float4 s_xy4[8192];   // 128 KB: entry e <-> points 2e, 2e+1
  __shared__ unsigned long long s_k[2][FPS_THREADS / 64];

  // dist for points p0 = k*1024 + 2t, p1 = p0+1, k = 0..15
#define DECLP(k) float dsA##k, dsB##k;
  REP16(DECLP)

  // prologue: copy dense xy plane into LDS (bit-exact), init dist
#define LOADP(k) { int e = (k) * FPS_THREADS + t;  \
    s_xy4[e] = xyb4[e];                            \
    dsA##k = FLT_MAX; dsB##k = FLT_MAX; }
  REP16(LOADP)

  const int wave = t >> 6;
  const int lane = t & 63;
  const unsigned invt2 = 0xFFFFFFFFu - (unsigned)(2 * t);
  int farthest = 0;

  __syncthreads();  // s_xy4 visible

  for (int s = 0; s < S; ++s) {
    if (t == 0) out_idx[(size_t)b * S + s] = farthest;

    // centroid: uniform index f -> LDS entry (f>>10)*512 + ((f&1023)>>1),
    // element j = f&1 ; z from dense plane (scalar L2 load, consumed last)
    int f = __builtin_amdgcn_readfirstlane(farthest);
    float cz = zb[f];
    float4 cq = s_xy4[(f >> 10) * FPS_THREADS + ((f & 1023) >> 1)];
    int j = f & 1;
    float cx = j ? cq.z : cq.x;
    float cy = j ? cq.w : cq.y;

    float bestv = -1.0f;
    int bestk = 0, bestj = 0;   // both fit inline constants in v_cndmask

    // FROZEN reference arithmetic; scan ascending (p0 then p1, k ascending)
#define STEPP(k) {                                               \
    int e = (k) * FPS_THREADS + t;                               \
    float4 q = s_xy4[e];                                         \
    float2 z2 = zb2[e];                                          \
    { float dx = q.x - cx, dy = q.y - cy, dz = z2.x - cz;        \
      float y2 = dy * dy;                                        \
      float inner = __builtin_fmaf(dx, dx, y2);                  \
      float dd = __builtin_fmaf(dz, dz, inner);                  \
      float nd = fminf(dsA##k, dd);                              \
      dsA##k = nd;                                               \
      if (nd > bestv) { bestv = nd; bestk = (k); bestj = 0; } }  \
    { float dx = q.z - cx, dy = q.w - cy, dz = z2.y - cz;        \
      float y2 = dy * dy;                                        \
      float inner = __builtin_fmaf(dx, dx, y2);                  \
      float dd = __builtin_fmaf(dz, dz, inner);                  \
      float nd = fminf(dsB##k, dd);                              \
      dsB##k = nd;                                               \
      if (nd > bestv) { bestv = nd; bestk = (k); bestj = 1; } } }
    REP16(STEPP)

    // inv original index: orig = bestk*1024 + 2t + bestj
    unsigned bestinv = invt2 - (unsigned)((bestk << 10) + bestj);

    // wave reduce via DPP (VALU pipe): max value, then max inv among ties
    float wmax = wave_maxf(bestv);
    unsigned cand = (bestv == wmax) ? bestinv : 0u;
    unsigned winv = wave_maxu(cand);

    // single barrier per step: parity double-buffer
    const int par = s & 1;
    if (lane == 0)
      s_k[par][wave] = ((unsigned long long)__float_as_uint(wmax) << 32) |
                       (unsigned long long)winv;
    __syncthreads();

    unsigned long long bk = s_k[par][0];
#pragma unroll
    for (int w = 1; w < FPS_THREADS / 64; ++w) {
      unsigned long long ok = s_k[par][w];
      if (ok > bk) bk = ok;
    }
    farthest = (int)(0xFFFFFFFFu - (unsigned)(bk & 0xFFFFFFFFu));
  }
}

// Gather: out = [ xyz[b][idx[b][s]][c] (B*S*3) , feat[b][idx[b][s]][:] (B*S*C) ]
__global__ void gather_kernel(const float* __restrict__ xyz,
                              const float* __restrict__ feat,
                              const int* __restrict__ idx,
                              float* __restrict__ out,
                              int B, int N, int S, int C) {
  const int c4pr = C >> 2;          // float4s per feat row
  const int nf4 = B * S * c4pr;     // total float4s of feat output
  int tid = blockIdx.x * blockDim.x + threadIdx.x;
  if (tid < nf4) {
    int c4 = tid % c4pr;
    int bs = tid / c4pr;
    int s = bs % S, b = bs / S;
    int p = idx[b * S + s];
    const float4* src = (const float4*)(feat + ((size_t)b * N + p) * C);
    float4* dst = (float4*)(out + (size_t)B * S * 3 + ((size_t)bs) * C);
    dst[c4] = src[c4];
  } else {
    int t2 = tid - nf4;
    int nxyz = B * S * 3;
    if (t2 < nxyz) {
      int c = t2 % 3;
      int bs = t2 / 3;
      int s = bs % S, b = bs / S;
      int p = idx[b * S + s];
      out[t2] = xyz[((size_t)b * N + p) * 3 + c];
    }
  }
}

extern "C" void kernel_launch(void* const* d_in, const int* in_sizes, int n_in,
                              void* d_out, int out_size, void* d_ws, size_t ws_size,
                              hipStream_t stream) {
  const float* xyz = (const float*)d_in[0];
  const float* feat = (const float*)d_in[1];
  float* out = (float*)d_out;

  const int B = 32;
  const int N = in_sizes[0] / (B * 3);        // 16384
  const int C = in_sizes[1] / (B * N);        // 128
  const int S = N / 4;                        // nsample = 0.25 * N = 4096

  // d_ws layout: idx (512KB) | xy planes (4MB, 16B-aligned) | z (2MB)
  int* d_idx = (int*)d_ws;
  float2* d_xy = (float2*)((char*)d_ws + (size_t)B * S * sizeof(int));
  float* d_z = (float*)((char*)d_xy + (size_t)B * N * sizeof(float2));

  transpose_kernel<<<B, FPS_THREADS, 0, stream>>>(xyz, d_xy, d_z, N);
  fps_kernel<<<B, FPS_THREADS, 0, stream>>>(d_xy, d_z, d_idx, N, S);

  int total = B * S * (C >> 2) + B * S * 3;
  int blocks = (total + 255) / 256;
  gather_kernel<<<blocks, 256, 0, stream>>>(xyz, feat, d_idx, out, B, N, S, C);
}